// Round 1
// baseline (1150.941 us; speedup 1.0000x reference)
//
#include <hip/hip_runtime.h>
#include <hip/hip_bf16.h>

#define N_NODES 50000
#define N_EDGES 600000
#define IN_F 256
#define OUT_F 128

// ---------------------------------------------------------------------------
// Kernel 1: support = x @ W   (fp32 vector GEMM, 64x128 tile, KB=32)
// block = 256 threads; each thread computes 8 rows x 4 cols (float4 acc[8]).
// ---------------------------------------------------------------------------
__global__ __launch_bounds__(256) void gcn_gemm(const float* __restrict__ x,
                                                const float* __restrict__ w,
                                                float* __restrict__ support) {
    __shared__ float As[64][32];    // 8 KB
    __shared__ float Bs[32][128];   // 16 KB
    const int t = threadIdx.x;
    const int block_row = blockIdx.x * 64;
    const int tx = t & 31;   // col group: cols tx*4 .. tx*4+3
    const int ty = t >> 5;   // row group: rows ty*8 .. ty*8+7

    float4 acc[8];
#pragma unroll
    for (int i = 0; i < 8; i++) acc[i] = make_float4(0.f, 0.f, 0.f, 0.f);

    for (int kb = 0; kb < IN_F; kb += 32) {
        // Load A tile: 64 rows x 32 k = 512 float4. idx = t + i*256.
#pragma unroll
        for (int i = 0; i < 2; i++) {
            int idx = t + i * 256;
            int row = idx >> 3;       // 8 float4 per row
            int k4  = idx & 7;
            int grow = block_row + row;
            float4 v = make_float4(0.f, 0.f, 0.f, 0.f);
            if (grow < N_NODES)
                v = *(const float4*)&x[(long long)grow * IN_F + kb + k4 * 4];
            *(float4*)&As[row][k4 * 4] = v;
        }
        // Load B tile: 32 k-rows x 128 cols = 1024 float4. idx = t + i*256.
#pragma unroll
        for (int i = 0; i < 4; i++) {
            int idx = t + i * 256;
            int krow = idx >> 5;      // 32 float4 per row
            int c4   = idx & 31;
            *(float4*)&Bs[krow][c4 * 4] =
                *(const float4*)&w[(long long)(kb + krow) * OUT_F + c4 * 4];
        }
        __syncthreads();

#pragma unroll
        for (int kk = 0; kk < 32; kk++) {
            float4 b = *(float4*)&Bs[kk][tx * 4];
#pragma unroll
            for (int r = 0; r < 8; r++) {
                float a = As[ty * 8 + r][kk];
                acc[r].x += a * b.x;
                acc[r].y += a * b.y;
                acc[r].z += a * b.z;
                acc[r].w += a * b.w;
            }
        }
        __syncthreads();
    }

#pragma unroll
    for (int r = 0; r < 8; r++) {
        int grow = block_row + ty * 8 + r;
        if (grow < N_NODES)
            *(float4*)&support[(long long)grow * OUT_F + tx * 4] = acc[r];
    }
}

// ---------------------------------------------------------------------------
// Kernel 2: out[n][f] = bias[f]   (harness poisons d_out with 0xAA)
// ---------------------------------------------------------------------------
__global__ __launch_bounds__(256) void gcn_init_out(float* __restrict__ out,
                                                    const float* __restrict__ bias) {
    int i = blockIdx.x * 256 + threadIdx.x;          // float4 index
    // total float4 = 50000*128/4 = 1,600,000 (grid sized exactly)
    float4 b = *(const float4*)&bias[(i & 31) * 4];  // 128/4 = 32 col-groups
    *(float4*)&out[(long long)i * 4] = b;
}

// ---------------------------------------------------------------------------
// Kernel 3: scatter-add  out[r] += val * support[c]  per edge.
// 32 lanes per edge, 4 floats (float4) per lane -> 4 atomicAdds per lane.
// ---------------------------------------------------------------------------
__global__ __launch_bounds__(256) void gcn_aggregate(const float* __restrict__ support,
                                                     const int* __restrict__ erows,
                                                     const int* __restrict__ ecols,
                                                     const float* __restrict__ evals,
                                                     float* __restrict__ out) {
    const int t = threadIdx.x;
    const int g = t >> 5;     // edge slot within block (0..7)
    const int l = t & 31;     // lane within edge group
    const long long e = (long long)blockIdx.x * 8 + g;
    if (e >= N_EDGES) return;

    const int r = erows[e];
    const int c = ecols[e];
    const float v = evals[e];

    float4 s = *(const float4*)&support[(long long)c * OUT_F + l * 4];
    float* o = &out[(long long)r * OUT_F + l * 4];
    atomicAdd(o + 0, v * s.x);
    atomicAdd(o + 1, v * s.y);
    atomicAdd(o + 2, v * s.z);
    atomicAdd(o + 3, v * s.w);
}

// ---------------------------------------------------------------------------
extern "C" void kernel_launch(void* const* d_in, const int* in_sizes, int n_in,
                              void* d_out, int out_size, void* d_ws, size_t ws_size,
                              hipStream_t stream) {
    const float* x     = (const float*)d_in[0];   // [50000, 256]
    const int*   erows = (const int*)d_in[1];     // [600000]
    const int*   ecols = (const int*)d_in[2];     // [600000]
    const float* evals = (const float*)d_in[3];   // [600000]
    const float* w     = (const float*)d_in[4];   // [256, 128]
    const float* bias  = (const float*)d_in[5];   // [128]
    float* out = (float*)d_out;                   // [50000, 128]

    float* support = (float*)d_ws;                // 50000*128*4 = 25.6 MB

    // 1) support = x @ W
    gcn_gemm<<<(N_NODES + 63) / 64, 256, 0, stream>>>(x, w, support);

    // 2) out = bias (broadcast)
    gcn_init_out<<<(N_NODES * OUT_F / 4) / 256, 256, 0, stream>>>(out, bias);

    // 3) out[r] += val * support[c] for each edge
    gcn_aggregate<<<(N_EDGES + 7) / 8, 256, 0, stream>>>(support, erows, ecols, evals, out);
}

// Round 2
// 265.247 us; speedup vs baseline: 4.3391x; 4.3391x over previous
//
#include <hip/hip_runtime.h>
#include <hip/hip_bf16.h>

#define N_NODES 50000
#define N_EDGES 600000
#define IN_F 256
#define OUT_F 128
#define SCAN_BLOCKS 196   // ceil(50000/256)

// ---------------------------------------------------------------------------
// Kernel 1: support = x @ W   (fp32 vector GEMM, 64x128 tile, KB=32)
// ---------------------------------------------------------------------------
__global__ __launch_bounds__(256) void gcn_gemm(const float* __restrict__ x,
                                                const float* __restrict__ w,
                                                float* __restrict__ support) {
    __shared__ float As[64][32];    // 8 KB
    __shared__ float Bs[32][128];   // 16 KB
    const int t = threadIdx.x;
    const int block_row = blockIdx.x * 64;
    const int tx = t & 31;   // col group: cols tx*4 .. tx*4+3
    const int ty = t >> 5;   // row group: rows ty*8 .. ty*8+7

    float4 acc[8];
#pragma unroll
    for (int i = 0; i < 8; i++) acc[i] = make_float4(0.f, 0.f, 0.f, 0.f);

    for (int kb = 0; kb < IN_F; kb += 32) {
#pragma unroll
        for (int i = 0; i < 2; i++) {
            int idx = t + i * 256;
            int row = idx >> 3;
            int k4  = idx & 7;
            int grow = block_row + row;
            float4 v = make_float4(0.f, 0.f, 0.f, 0.f);
            if (grow < N_NODES)
                v = *(const float4*)&x[(long long)grow * IN_F + kb + k4 * 4];
            *(float4*)&As[row][k4 * 4] = v;
        }
#pragma unroll
        for (int i = 0; i < 4; i++) {
            int idx = t + i * 256;
            int krow = idx >> 5;
            int c4   = idx & 31;
            *(float4*)&Bs[krow][c4 * 4] =
                *(const float4*)&w[(long long)(kb + krow) * OUT_F + c4 * 4];
        }
        __syncthreads();

#pragma unroll
        for (int kk = 0; kk < 32; kk++) {
            float4 b = *(float4*)&Bs[kk][tx * 4];
#pragma unroll
            for (int r = 0; r < 8; r++) {
                float a = As[ty * 8 + r][kk];
                acc[r].x += a * b.x;
                acc[r].y += a * b.y;
                acc[r].z += a * b.z;
                acc[r].w += a * b.w;
            }
        }
        __syncthreads();
    }

#pragma unroll
    for (int r = 0; r < 8; r++) {
        int grow = block_row + ty * 8 + r;
        if (grow < N_NODES)
            *(float4*)&support[(long long)grow * OUT_F + tx * 4] = acc[r];
    }
}

// ---------------------------------------------------------------------------
// CSR build: zero -> histogram -> 2-level exclusive scan -> cursor scatter
// ---------------------------------------------------------------------------
__global__ __launch_bounds__(256) void gcn_zero_counts(int* __restrict__ counts) {
    int i = blockIdx.x * 256 + threadIdx.x;
    if (i < N_NODES) counts[i] = 0;
}

__global__ __launch_bounds__(256) void gcn_hist(const int* __restrict__ erows,
                                                int* __restrict__ counts) {
    int e = blockIdx.x * 256 + threadIdx.x;
    if (e < N_EDGES) atomicAdd(&counts[erows[e]], 1);
}

// per-block exclusive scan; block sums to partials
__global__ __launch_bounds__(256) void gcn_scan1(const int* __restrict__ counts,
                                                 int* __restrict__ row_start,
                                                 int* __restrict__ partials) {
    __shared__ int s[256];
    const int t = threadIdx.x;
    const int i = blockIdx.x * 256 + t;
    int v = (i < N_NODES) ? counts[i] : 0;
    s[t] = v;
    __syncthreads();
#pragma unroll
    for (int off = 1; off < 256; off <<= 1) {
        int x = (t >= off) ? s[t - off] : 0;
        __syncthreads();
        s[t] += x;
        __syncthreads();
    }
    if (i < N_NODES) row_start[i] = s[t] - v;   // exclusive within block
    if (t == 255) partials[blockIdx.x] = s[255];
}

// single-block exclusive scan of the 196 partials
__global__ __launch_bounds__(256) void gcn_scan2(int* __restrict__ partials) {
    __shared__ int s[256];
    const int t = threadIdx.x;
    int v = (t < SCAN_BLOCKS) ? partials[t] : 0;
    s[t] = v;
    __syncthreads();
#pragma unroll
    for (int off = 1; off < 256; off <<= 1) {
        int x = (t >= off) ? s[t - off] : 0;
        __syncthreads();
        s[t] += x;
        __syncthreads();
    }
    if (t < SCAN_BLOCKS) partials[t] = s[t] - v;  // exclusive
}

__global__ __launch_bounds__(256) void gcn_scan3(int* __restrict__ row_start,
                                                 int* __restrict__ cursor,
                                                 const int* __restrict__ partials) {
    const int i = blockIdx.x * 256 + threadIdx.x;
    if (i < N_NODES) {
        int rs = row_start[i] + partials[blockIdx.x];
        row_start[i] = rs;
        cursor[i] = rs;
    }
    if (i == 0) row_start[N_NODES] = N_EDGES;
}

__global__ __launch_bounds__(256) void gcn_scatter(const int* __restrict__ erows,
                                                   const int* __restrict__ ecols,
                                                   const float* __restrict__ evals,
                                                   int* __restrict__ cursor,
                                                   int* __restrict__ sorted_col,
                                                   float* __restrict__ sorted_val) {
    int e = blockIdx.x * 256 + threadIdx.x;
    if (e < N_EDGES) {
        int r = erows[e];
        int pos = atomicAdd(&cursor[r], 1);
        sorted_col[pos] = ecols[e];
        sorted_val[pos] = evals[e];
    }
}

// ---------------------------------------------------------------------------
// Aggregate: one 64-lane wave per node; float2 per lane covers 128 cols.
// out[n] = bias + sum_{e in row n} val_e * support[col_e]
// ---------------------------------------------------------------------------
__global__ __launch_bounds__(256) void gcn_aggregate_csr(const float* __restrict__ support,
                                                         const int* __restrict__ sorted_col,
                                                         const float* __restrict__ sorted_val,
                                                         const int* __restrict__ row_start,
                                                         const float* __restrict__ bias,
                                                         float* __restrict__ out) {
    const int node = (blockIdx.x * 256 + threadIdx.x) >> 6;
    const int lane = threadIdx.x & 63;
    if (node >= N_NODES) return;

    const int beg = row_start[node];
    const int end = row_start[node + 1];

    float2 acc = *(const float2*)&bias[lane * 2];

    int i = beg;
    for (; i + 1 < end; i += 2) {
        int   c0 = sorted_col[i];
        int   c1 = sorted_col[i + 1];
        float v0 = sorted_val[i];
        float v1 = sorted_val[i + 1];
        float2 s0 = *(const float2*)&support[(long long)c0 * OUT_F + lane * 2];
        float2 s1 = *(const float2*)&support[(long long)c1 * OUT_F + lane * 2];
        acc.x += v0 * s0.x + v1 * s1.x;
        acc.y += v0 * s0.y + v1 * s1.y;
    }
    if (i < end) {
        int   c = sorted_col[i];
        float v = sorted_val[i];
        float2 s = *(const float2*)&support[(long long)c * OUT_F + lane * 2];
        acc.x += v * s.x;
        acc.y += v * s.y;
    }

    *(float2*)&out[(long long)node * OUT_F + lane * 2] = acc;
}

// ---------------------------------------------------------------------------
extern "C" void kernel_launch(void* const* d_in, const int* in_sizes, int n_in,
                              void* d_out, int out_size, void* d_ws, size_t ws_size,
                              hipStream_t stream) {
    const float* x     = (const float*)d_in[0];   // [50000, 256]
    const int*   erows = (const int*)d_in[1];     // [600000]
    const int*   ecols = (const int*)d_in[2];     // [600000]
    const float* evals = (const float*)d_in[3];   // [600000]
    const float* w     = (const float*)d_in[4];   // [256, 128]
    const float* bias  = (const float*)d_in[5];   // [128]
    float* out = (float*)d_out;                   // [50000, 128]

    // workspace layout
    float* support    = (float*)d_ws;                          // 6.4M floats (25.6 MB)
    char*  p          = (char*)d_ws + (size_t)N_NODES * OUT_F * 4;
    int*   counts     = (int*)p;            p += (size_t)N_NODES * 4;
    int*   row_start  = (int*)p;            p += (size_t)(N_NODES + 1) * 4;
    int*   cursor     = (int*)p;            p += (size_t)N_NODES * 4;
    int*   partials   = (int*)p;            p += 256 * 4;
    int*   sorted_col = (int*)p;            p += (size_t)N_EDGES * 4;
    float* sorted_val = (float*)p;

    const int eblocks = (N_EDGES + 255) / 256;

    // GEMM: support = x @ W
    gcn_gemm<<<(N_NODES + 63) / 64, 256, 0, stream>>>(x, w, support);

    // CSR build
    gcn_zero_counts<<<SCAN_BLOCKS, 256, 0, stream>>>(counts);
    gcn_hist<<<eblocks, 256, 0, stream>>>(erows, counts);
    gcn_scan1<<<SCAN_BLOCKS, 256, 0, stream>>>(counts, row_start, partials);
    gcn_scan2<<<1, 256, 0, stream>>>(partials);
    gcn_scan3<<<SCAN_BLOCKS, 256, 0, stream>>>(row_start, cursor, partials);
    gcn_scatter<<<eblocks, 256, 0, stream>>>(erows, ecols, evals, cursor,
                                             sorted_col, sorted_val);

    // Aggregate + bias (one wave per node, 4 nodes per block)
    gcn_aggregate_csr<<<(N_NODES + 3) / 4, 256, 0, stream>>>(
        support, sorted_col, sorted_val, row_start, bias, out);
}

// Round 3
// 224.426 us; speedup vs baseline: 5.1284x; 1.1819x over previous
//
#include <hip/hip_runtime.h>
#include <hip/hip_bf16.h>

#define N_NODES 50000
#define N_EDGES 600000
#define IN_F 256
#define OUT_F 128
#define SCAN_BLOCKS 196   // ceil(50000/256)

typedef __bf16 bf16x8 __attribute__((ext_vector_type(8)));
typedef __bf16 bf16x2 __attribute__((ext_vector_type(2)));
typedef float  f32x4  __attribute__((ext_vector_type(4)));

// ---------------------------------------------------------------------------
// Kernel 0: Wt[n][k] = bf16(W[k][n])  (transpose+convert, 64 KB, done once)
// ---------------------------------------------------------------------------
__global__ __launch_bounds__(256) void gcn_wt(const float* __restrict__ w,
                                              __bf16* __restrict__ wt) {
    const int n = blockIdx.x;    // 0..127
    const int k = threadIdx.x;   // 0..255
    wt[n * IN_F + k] = (__bf16)w[k * OUT_F + n];
}

// ---------------------------------------------------------------------------
// Kernel 1: support = bf16(x @ W) via MFMA 16x16x32, LDS-free.
// One wave per 16-row tile; 8 n-tiles x 8 k-steps; A from global x (fp32->bf16
// inline, quad-contiguous 128B segments), B from pre-transposed Wt (L2-hot).
// ---------------------------------------------------------------------------
__global__ __launch_bounds__(256) void gcn_gemm_mfma(const float* __restrict__ x,
                                                     const __bf16* __restrict__ wt,
                                                     __bf16* __restrict__ support) {
    const int lane = threadIdx.x & 63;
    const int wave = threadIdx.x >> 6;
    const int tile = blockIdx.x * 4 + wave;    // 16-row tile
    const int row_base = tile * 16;
    if (row_base >= N_NODES) return;           // no barriers in kernel: safe
    const int m    = lane & 15;
    const int quad = lane >> 4;

    f32x4 acc[8];
#pragma unroll
    for (int nt = 0; nt < 8; nt++) acc[nt] = (f32x4){0.f, 0.f, 0.f, 0.f};

    const float*  xrow = x  + (size_t)(row_base + m) * IN_F + quad * 8;
    const __bf16* wrow = wt + (size_t)m * IN_F + quad * 8;

#pragma unroll
    for (int ks = 0; ks < 8; ks++) {
        float4 a0 = *(const float4*)(xrow + ks * 32);
        float4 a1 = *(const float4*)(xrow + ks * 32 + 4);
        bf16x8 af = { (__bf16)a0.x, (__bf16)a0.y, (__bf16)a0.z, (__bf16)a0.w,
                      (__bf16)a1.x, (__bf16)a1.y, (__bf16)a1.z, (__bf16)a1.w };
#pragma unroll
        for (int nt = 0; nt < 8; nt++) {
            bf16x8 bf = *(const bf16x8*)(wrow + (size_t)nt * 16 * IN_F + ks * 32);
            acc[nt] = __builtin_amdgcn_mfma_f32_16x16x32_bf16(af, bf, acc[nt], 0, 0, 0);
        }
    }

    // C/D layout: col = lane&15, row = quad*4 + reg  [m89-verified]
#pragma unroll
    for (int nt = 0; nt < 8; nt++) {
#pragma unroll
        for (int r = 0; r < 4; r++) {
            int mrow = row_base + quad * 4 + r;
            support[(size_t)mrow * OUT_F + nt * 16 + m] = (__bf16)acc[nt][r];
        }
    }
}

// ---------------------------------------------------------------------------
// CSR build: zero -> histogram(+rank) -> 2-level exclusive scan -> scatter
// ---------------------------------------------------------------------------
__global__ __launch_bounds__(256) void gcn_zero_counts(int* __restrict__ counts) {
    int i = blockIdx.x * 256 + threadIdx.x;
    if (i < N_NODES) counts[i] = 0;
}

__global__ __launch_bounds__(256) void gcn_hist(const int* __restrict__ erows,
                                                int* __restrict__ counts,
                                                int* __restrict__ rank) {
    int e = blockIdx.x * 256 + threadIdx.x;
    if (e < N_EDGES) rank[e] = atomicAdd(&counts[erows[e]], 1);
}

__global__ __launch_bounds__(256) void gcn_scan1(const int* __restrict__ counts,
                                                 int* __restrict__ row_start,
                                                 int* __restrict__ partials) {
    __shared__ int s[256];
    const int t = threadIdx.x;
    const int i = blockIdx.x * 256 + t;
    int v = (i < N_NODES) ? counts[i] : 0;
    s[t] = v;
    __syncthreads();
#pragma unroll
    for (int off = 1; off < 256; off <<= 1) {
        int x = (t >= off) ? s[t - off] : 0;
        __syncthreads();
        s[t] += x;
        __syncthreads();
    }
    if (i < N_NODES) row_start[i] = s[t] - v;
    if (t == 255) partials[blockIdx.x] = s[255];
}

__global__ __launch_bounds__(256) void gcn_scan2(int* __restrict__ partials) {
    __shared__ int s[256];
    const int t = threadIdx.x;
    int v = (t < SCAN_BLOCKS) ? partials[t] : 0;
    s[t] = v;
    __syncthreads();
#pragma unroll
    for (int off = 1; off < 256; off <<= 1) {
        int x = (t >= off) ? s[t - off] : 0;
        __syncthreads();
        s[t] += x;
        __syncthreads();
    }
    if (t < SCAN_BLOCKS) partials[t] = s[t] - v;
}

__global__ __launch_bounds__(256) void gcn_scan3(int* __restrict__ row_start,
                                                 const int* __restrict__ partials) {
    const int i = blockIdx.x * 256 + threadIdx.x;
    if (i < N_NODES) row_start[i] += partials[blockIdx.x];
    if (i == 0) row_start[N_NODES] = N_EDGES;
}

__global__ __launch_bounds__(256) void gcn_scatter(const int* __restrict__ erows,
                                                   const int* __restrict__ ecols,
                                                   const float* __restrict__ evals,
                                                   const int* __restrict__ row_start,
                                                   const int* __restrict__ rank,
                                                   int* __restrict__ sorted_col,
                                                   float* __restrict__ sorted_val) {
    int e = blockIdx.x * 256 + threadIdx.x;
    if (e < N_EDGES) {
        int pos = row_start[erows[e]] + rank[e];
        sorted_col[pos] = ecols[e];
        sorted_val[pos] = evals[e];
    }
}

// ---------------------------------------------------------------------------
// Aggregate: one wave per node; bfloat162 per lane covers 128 cols (256B/row).
// out[n] = bias + sum_{e in row n} val_e * support[col_e]
// ---------------------------------------------------------------------------
__global__ __launch_bounds__(256) void gcn_aggregate_csr(const __bf16* __restrict__ support,
                                                         const int* __restrict__ sorted_col,
                                                         const float* __restrict__ sorted_val,
                                                         const int* __restrict__ row_start,
                                                         const float* __restrict__ bias,
                                                         float* __restrict__ out) {
    const int node = (blockIdx.x * 256 + threadIdx.x) >> 6;
    const int lane = threadIdx.x & 63;
    if (node >= N_NODES) return;

    const int beg = row_start[node];
    const int end = row_start[node + 1];

    float2 acc = *(const float2*)&bias[lane * 2];
    const __bf16* sp = support + lane * 2;

    int i = beg;
    for (; i + 1 < end; i += 2) {
        int   c0 = sorted_col[i];
        int   c1 = sorted_col[i + 1];
        float v0 = sorted_val[i];
        float v1 = sorted_val[i + 1];
        bf16x2 s0 = *(const bf16x2*)(sp + (size_t)c0 * OUT_F);
        bf16x2 s1 = *(const bf16x2*)(sp + (size_t)c1 * OUT_F);
        acc.x += v0 * (float)s0.x + v1 * (float)s1.x;
        acc.y += v0 * (float)s0.y + v1 * (float)s1.y;
    }
    if (i < end) {
        int   c = sorted_col[i];
        float v = sorted_val[i];
        bf16x2 s = *(const bf16x2*)(sp + (size_t)c * OUT_F);
        acc.x += v * (float)s.x;
        acc.y += v * (float)s.y;
    }

    *(float2*)&out[(size_t)node * OUT_F + lane * 2] = acc;
}

// ---------------------------------------------------------------------------
extern "C" void kernel_launch(void* const* d_in, const int* in_sizes, int n_in,
                              void* d_out, int out_size, void* d_ws, size_t ws_size,
                              hipStream_t stream) {
    const float* x     = (const float*)d_in[0];   // [50000, 256]
    const int*   erows = (const int*)d_in[1];     // [600000]
    const int*   ecols = (const int*)d_in[2];     // [600000]
    const float* evals = (const float*)d_in[3];   // [600000]
    const float* w     = (const float*)d_in[4];   // [256, 128]
    const float* bias  = (const float*)d_in[5];   // [128]
    float* out = (float*)d_out;                   // [50000, 128]

    // workspace layout (~20.5 MB)
    __bf16* support   = (__bf16*)d_ws;                           // 12.8 MB
    char*   p         = (char*)d_ws + (size_t)N_NODES * OUT_F * 2;
    __bf16* wt        = (__bf16*)p;  p += (size_t)IN_F * OUT_F * 2;   // 64 KB
    int*    counts    = (int*)p;     p += (size_t)N_NODES * 4;
    int*    row_start = (int*)p;     p += (size_t)(N_NODES + 1) * 4;
    int*    rank      = (int*)p;     p += (size_t)N_EDGES * 4;
    int*    partials  = (int*)p;     p += 256 * 4;
    int*    sorted_col= (int*)p;     p += (size_t)N_EDGES * 4;
    float*  sorted_val= (float*)p;

    const int eblocks = (N_EDGES + 255) / 256;

    // GEMM path
    gcn_wt<<<OUT_F, IN_F, 0, stream>>>(w, wt);
    gcn_gemm_mfma<<<(N_NODES / 16 + 3) / 4, 256, 0, stream>>>(x, wt, support);

    // CSR build
    gcn_zero_counts<<<SCAN_BLOCKS, 256, 0, stream>>>(counts);
    gcn_hist<<<eblocks, 256, 0, stream>>>(erows, counts, rank);
    gcn_scan1<<<SCAN_BLOCKS, 256, 0, stream>>>(counts, row_start, partials);
    gcn_scan2<<<1, 256, 0, stream>>>(partials);
    gcn_scan3<<<SCAN_BLOCKS, 256, 0, stream>>>(row_start, partials);
    gcn_scatter<<<eblocks, 256, 0, stream>>>(erows, ecols, evals, row_start, rank,
                                             sorted_col, sorted_val);

    // Aggregate + bias (one wave per node, 4 nodes per block)
    gcn_aggregate_csr<<<(N_NODES + 3) / 4, 256, 0, stream>>>(
        support, sorted_col, sorted_val, row_start, bias, out);
}

// Round 4
// 203.651 us; speedup vs baseline: 5.6515x; 1.1020x over previous
//
#include <hip/hip_runtime.h>
#include <hip/hip_bf16.h>

#define N_NODES 50000
#define N_EDGES 600000
#define IN_F 256
#define OUT_F 128
#define SCAN_BLOCKS 196   // ceil(50000/256)
#define LDS_K (IN_F + 8)  // +8 bf16 (16B) row pad: b128 frag reads hit all 8 bank-groups

typedef __bf16 bf16x8 __attribute__((ext_vector_type(8)));
typedef __bf16 bf16x2 __attribute__((ext_vector_type(2)));
typedef float  f32x4  __attribute__((ext_vector_type(4)));

// ---------------------------------------------------------------------------
// Kernel 0 (fused prep): wt[n][k] = bf16(W[k][n])  +  counts[] = 0
// ---------------------------------------------------------------------------
__global__ __launch_bounds__(256) void gcn_prep(const float* __restrict__ w,
                                                __bf16* __restrict__ wt,
                                                int* __restrict__ counts) {
    int i = blockIdx.x * 256 + threadIdx.x;
    if (i < N_NODES) counts[i] = 0;
    if (i < IN_F * OUT_F) {
        int k = i >> 7;          // consecutive i -> consecutive n: coalesced w read
        int n = i & 127;
        wt[n * IN_F + k] = (__bf16)w[i];
    }
}

// ---------------------------------------------------------------------------
// Kernel 1: support = bf16(x @ W) via MFMA 16x16x32.
// Block = 4 waves; wt staged in padded LDS (66 KB); each wave owns 2 m-tiles
// (32 rows); block covers 128 rows; grid covers all 50000 rows in one pass.
// ---------------------------------------------------------------------------
__global__ __launch_bounds__(256) void gcn_gemm_mfma(const float* __restrict__ x,
                                                     const __bf16* __restrict__ wt,
                                                     __bf16* __restrict__ support) {
    __shared__ __bf16 bs[OUT_F * LDS_K];   // 128 * 264 * 2 B = 66 KB

    const int t = threadIdx.x;
    // ---- stage wt -> LDS (coalesced 16B chunks; 16 chunks per thread) ----
#pragma unroll
    for (int i = 0; i < 16; i++) {
        int c  = i * 256 + t;        // chunk id 0..4095 (32 chunks of bf16x8 per n-row)
        int n  = c >> 5;
        int kc = c & 31;
        *(bf16x8*)&bs[n * LDS_K + kc * 8] = *(const bf16x8*)&wt[n * IN_F + kc * 8];
    }
    __syncthreads();

    const int wave = t >> 6;
    const int lane = t & 63;
    const int m    = lane & 15;
    const int quad = lane >> 4;
    const int row0 = blockIdx.x * 128 + wave * 32;   // this wave: rows row0..row0+31

    int r0 = row0 + m;
    int r1 = row0 + 16 + m;
    const float* xp0 = x + (size_t)(r0 < N_NODES ? r0 : 0) * IN_F + quad * 8;
    const float* xp1 = x + (size_t)(r1 < N_NODES ? r1 : 0) * IN_F + quad * 8;

    f32x4 acc0[8], acc1[8];
#pragma unroll
    for (int nt = 0; nt < 8; nt++) {
        acc0[nt] = (f32x4){0.f, 0.f, 0.f, 0.f};
        acc1[nt] = (f32x4){0.f, 0.f, 0.f, 0.f};
    }

#pragma unroll
    for (int ks = 0; ks < 8; ks++) {
        float4 a00 = *(const float4*)(xp0 + ks * 32);
        float4 a01 = *(const float4*)(xp0 + ks * 32 + 4);
        float4 a10 = *(const float4*)(xp1 + ks * 32);
        float4 a11 = *(const float4*)(xp1 + ks * 32 + 4);
        bf16x8 af0 = { (__bf16)a00.x, (__bf16)a00.y, (__bf16)a00.z, (__bf16)a00.w,
                       (__bf16)a01.x, (__bf16)a01.y, (__bf16)a01.z, (__bf16)a01.w };
        bf16x8 af1 = { (__bf16)a10.x, (__bf16)a10.y, (__bf16)a10.z, (__bf16)a10.w,
                       (__bf16)a11.x, (__bf16)a11.y, (__bf16)a11.z, (__bf16)a11.w };
#pragma unroll
        for (int nt = 0; nt < 8; nt++) {
            bf16x8 bf = *(const bf16x8*)&bs[(nt * 16 + m) * LDS_K + ks * 32 + quad * 8];
            acc0[nt] = __builtin_amdgcn_mfma_f32_16x16x32_bf16(af0, bf, acc0[nt], 0, 0, 0);
            acc1[nt] = __builtin_amdgcn_mfma_f32_16x16x32_bf16(af1, bf, acc1[nt], 0, 0, 0);
        }
    }

    // C/D layout: col = lane&15, row = quad*4 + reg  [m89-verified]
#pragma unroll
    for (int nt = 0; nt < 8; nt++) {
#pragma unroll
        for (int r = 0; r < 4; r++) {
            int ra = row0 + quad * 4 + r;
            if (ra < N_NODES)
                support[(size_t)ra * OUT_F + nt * 16 + m] = (__bf16)acc0[nt][r];
            int rb = ra + 16;
            if (rb < N_NODES)
                support[(size_t)rb * OUT_F + nt * 16 + m] = (__bf16)acc1[nt][r];
        }
    }
}

// ---------------------------------------------------------------------------
// CSR build: histogram(+rank) -> 2-level exclusive scan -> packed scatter
// ---------------------------------------------------------------------------
__global__ __launch_bounds__(256) void gcn_hist(const int* __restrict__ erows,
                                                int* __restrict__ counts,
                                                int* __restrict__ rank) {
    int e = blockIdx.x * 256 + threadIdx.x;
    if (e < N_EDGES) rank[e] = atomicAdd(&counts[erows[e]], 1);
}

__global__ __launch_bounds__(256) void gcn_scan1(const int* __restrict__ counts,
                                                 int* __restrict__ row_start,
                                                 int* __restrict__ partials) {
    __shared__ int s[256];
    const int t = threadIdx.x;
    const int i = blockIdx.x * 256 + t;
    int v = (i < N_NODES) ? counts[i] : 0;
    s[t] = v;
    __syncthreads();
#pragma unroll
    for (int off = 1; off < 256; off <<= 1) {
        int x = (t >= off) ? s[t - off] : 0;
        __syncthreads();
        s[t] += x;
        __syncthreads();
    }
    if (i < N_NODES) row_start[i] = s[t] - v;
    if (t == 255) partials[blockIdx.x] = s[255];
}

__global__ __launch_bounds__(256) void gcn_scan2(int* __restrict__ partials) {
    __shared__ int s[256];
    const int t = threadIdx.x;
    int v = (t < SCAN_BLOCKS) ? partials[t] : 0;
    s[t] = v;
    __syncthreads();
#pragma unroll
    for (int off = 1; off < 256; off <<= 1) {
        int x = (t >= off) ? s[t - off] : 0;
        __syncthreads();
        s[t] += x;
        __syncthreads();
    }
    if (t < SCAN_BLOCKS) partials[t] = s[t] - v;
}

__global__ __launch_bounds__(256) void gcn_scan3(int* __restrict__ row_start,
                                                 const int* __restrict__ partials) {
    const int i = blockIdx.x * 256 + threadIdx.x;
    if (i < N_NODES) row_start[i] += partials[blockIdx.x];
    if (i == 0) row_start[N_NODES] = N_EDGES;
}

__global__ __launch_bounds__(256) void gcn_scatter(const int* __restrict__ erows,
                                                   const int* __restrict__ ecols,
                                                   const float* __restrict__ evals,
                                                   const int* __restrict__ row_start,
                                                   const int* __restrict__ rank,
                                                   int2* __restrict__ sorted_cv) {
    int e = blockIdx.x * 256 + threadIdx.x;
    if (e < N_EDGES) {
        int pos = row_start[erows[e]] + rank[e];
        sorted_cv[pos] = make_int2(ecols[e], __float_as_int(evals[e]));
    }
}

// ---------------------------------------------------------------------------
// Aggregate: one wave per node; bf16x2 per lane covers 128 cols (256 B row).
// out[n] = bias + sum_{e in row n} val_e * support[col_e]
// ---------------------------------------------------------------------------
__global__ __launch_bounds__(256) void gcn_aggregate_csr(const __bf16* __restrict__ support,
                                                         const int2* __restrict__ sorted_cv,
                                                         const int* __restrict__ row_start,
                                                         const float* __restrict__ bias,
                                                         float* __restrict__ out) {
    const int node = (blockIdx.x * 256 + threadIdx.x) >> 6;
    const int lane = threadIdx.x & 63;
    if (node >= N_NODES) return;

    const int beg = row_start[node];
    const int end = row_start[node + 1];

    float2 acc = *(const float2*)&bias[lane * 2];
    const __bf16* sp = support + lane * 2;

    int i = beg;
    for (; i + 1 < end; i += 2) {
        int2 cv0 = sorted_cv[i];
        int2 cv1 = sorted_cv[i + 1];
        float v0 = __int_as_float(cv0.y);
        float v1 = __int_as_float(cv1.y);
        bf16x2 s0 = *(const bf16x2*)(sp + (size_t)cv0.x * OUT_F);
        bf16x2 s1 = *(const bf16x2*)(sp + (size_t)cv1.x * OUT_F);
        acc.x += v0 * (float)s0.x + v1 * (float)s1.x;
        acc.y += v0 * (float)s0.y + v1 * (float)s1.y;
    }
    if (i < end) {
        int2 cv = sorted_cv[i];
        float v = __int_as_float(cv.y);
        bf16x2 s = *(const bf16x2*)(sp + (size_t)cv.x * OUT_F);
        acc.x += v * (float)s.x;
        acc.y += v * (float)s.y;
    }

    *(float2*)&out[(size_t)node * OUT_F + lane * 2] = acc;
}

// ---------------------------------------------------------------------------
static inline size_t align_up(size_t v, size_t a) { return (v + a - 1) & ~(a - 1); }

extern "C" void kernel_launch(void* const* d_in, const int* in_sizes, int n_in,
                              void* d_out, int out_size, void* d_ws, size_t ws_size,
                              hipStream_t stream) {
    const float* x     = (const float*)d_in[0];   // [50000, 256]
    const int*   erows = (const int*)d_in[1];     // [600000]
    const int*   ecols = (const int*)d_in[2];     // [600000]
    const float* evals = (const float*)d_in[3];   // [600000]
    const float* w     = (const float*)d_in[4];   // [256, 128]
    const float* bias  = (const float*)d_in[5];   // [128]
    float* out = (float*)d_out;                   // [50000, 128]

    // workspace layout (all regions 64B-aligned; ~20.7 MB total)
    size_t off = 0;
    __bf16* support   = (__bf16*)((char*)d_ws + off);
    off = align_up(off + (size_t)N_NODES * OUT_F * 2, 64);
    __bf16* wt        = (__bf16*)((char*)d_ws + off);
    off = align_up(off + (size_t)IN_F * OUT_F * 2, 64);
    int*    counts    = (int*)((char*)d_ws + off);
    off = align_up(off + (size_t)N_NODES * 4, 64);
    int*    row_start = (int*)((char*)d_ws + off);
    off = align_up(off + (size_t)(N_NODES + 1) * 4, 64);
    int*    rank      = (int*)((char*)d_ws + off);
    off = align_up(off + (size_t)N_EDGES * 4, 64);
    int*    partials  = (int*)((char*)d_ws + off);
    off = align_up(off + 256 * 4, 64);
    int2*   sorted_cv = (int2*)((char*)d_ws + off);

    const int eblocks = (N_EDGES + 255) / 256;

    // prep: wt transpose + counts zero (independent work, one launch)
    gcn_prep<<<SCAN_BLOCKS, 256, 0, stream>>>(w, wt, counts);

    // GEMM: support = bf16(x @ W)
    gcn_gemm_mfma<<<(N_NODES + 127) / 128, 256, 0, stream>>>(x, wt, support);

    // CSR build
    gcn_hist<<<eblocks, 256, 0, stream>>>(erows, counts, rank);
    gcn_scan1<<<SCAN_BLOCKS, 256, 0, stream>>>(counts, row_start, partials);
    gcn_scan2<<<1, 256, 0, stream>>>(partials);
    gcn_scan3<<<SCAN_BLOCKS, 256, 0, stream>>>(row_start, partials);
    gcn_scatter<<<eblocks, 256, 0, stream>>>(erows, ecols, evals, row_start, rank,
                                             sorted_cv);

    // Aggregate + bias (one wave per node, 4 nodes per block)
    gcn_aggregate_csr<<<(N_NODES + 3) / 4, 256, 0, stream>>>(
        support, sorted_cv, row_start, bias, out);
}